// Round 9
// baseline (102.718 us; speedup 1.0000x reference)
//
#include <hip/hip_runtime.h>

#define HH 48
#define WWD 48
#define CC 256
#define OCC 256
#define NPIX 2304
#define NB 2
#define NHEADS 4
#define DHEAD 64
#define SCALE_E 0.1803368802f   // 0.125 * log2(e); softmax via exp2

// attention tiling: 2x16 pixel tile, 6x20 patch
#define TH 2
#define TW 16
#define PHR 6
#define PWC 20
#define NPOS 120            // PHR*PWC
#define NTILES 72           // (48/2)*(48/16)

#define SLAB ((size_t)NPIX * OCC)   // elements (bf16 ushort)

typedef __attribute__((ext_vector_type(8))) short short8v;
typedef __attribute__((ext_vector_type(4))) float floatx4;

__device__ __forceinline__ unsigned short f2bf(float f) {
    union { float f; unsigned u; } v; v.f = f;
    unsigned r = v.u + 0x7FFFu + ((v.u >> 16) & 1u);   // RNE
    return (unsigned short)(r >> 16);
}
__device__ __forceinline__ float bf2f(unsigned short b) {
    union { unsigned u; float f; } v; v.u = ((unsigned)b) << 16; return v.f;
}

// 8-lane (bits 0..2) all-reduce sum: xor1/xor2 via DPP quad_perm (VALU pipe),
// xor4 via one ds_swizzle.
__device__ __forceinline__ float xreduce8(float s) {
    s += __int_as_float(__builtin_amdgcn_update_dpp(
        0, __float_as_int(s), 0xB1, 0xf, 0xf, true));   // [1,0,3,2]
    s += __int_as_float(__builtin_amdgcn_update_dpp(
        0, __float_as_int(s), 0x4E, 0xf, 0xf, true));   // [2,3,0,1]
    s += __shfl_xor(s, 4, 64);
    return s;
}

// ---------------------------------------------------------------------------
// MFMA projection (structure validated R7): out[x][o] = sum_c W[o][c]*X[c][x],
// A = W hi/lo bf16 split loaded directly from global; B = X^T staged to LDS
// as bf16-hi via in-register 4x4 transpose with 8B XOR swizzle.
// NEW: output slabs stored as BF16 (halves store traffic; attn already
// consumed k in bf16, so k-path precision is unchanged; q gains one bf16
// rounding, ~1e-3 logit-level).
// ---------------------------------------------------------------------------
__global__ __launch_bounds__(256) void proj_mfma(
    const float* __restrict__ Wq, const float* __restrict__ Wkv,
    const float* __restrict__ qmap, const float* __restrict__ kv1,
    const float* __restrict__ kv2, unsigned short* __restrict__ ws)
{
    __shared__ unsigned short Bs[64 * 64];   // 8 KB, [x][k] bf16 swizzled

    const int z = blockIdx.z;
    const int map = z % 3;
    const int b = z / 3;
    const float* Wmat = (map == 0) ? Wq : Wkv;
    const float* X = ((map == 0) ? qmap : (map == 1) ? kv1 : kv2)
                     + (size_t)b * CC * NPIX;
    unsigned short* out = ws + ((size_t)map * NB + b) * SLAB;

    const int tid = threadIdx.x;
    const int x0 = blockIdx.x * 64;
    const int o0 = blockIdx.y * 64;
    const int lane = tid & 63;
    const int wv = tid >> 6;
    const int l15 = lane & 15;
    const int l4 = lane >> 4;
    const int kq_w = tid >> 4;     // 0..15: k-quad this thread stages
    const int xq = tid & 15;       // 0..15: x-quad this thread stages

    const float* Arow = Wmat + (size_t)(o0 + wv * 16 + l15) * CC;

    floatx4 acc[4];
#pragma unroll
    for (int nt = 0; nt < 4; ++nt) acc[nt] = (floatx4){0.f, 0.f, 0.f, 0.f};

#pragma unroll
    for (int kt = 0; kt < 4; ++kt) {
        const int k0t = kt * 64;

        float4 av0 = *reinterpret_cast<const float4*>(Arow + k0t + l4 * 8);
        float4 av1 = *reinterpret_cast<const float4*>(Arow + k0t + l4 * 8 + 4);
        float4 av2 = *reinterpret_cast<const float4*>(Arow + k0t + 32 + l4 * 8);
        float4 av3 = *reinterpret_cast<const float4*>(Arow + k0t + 32 + l4 * 8 + 4);

        float4 xv[4];
#pragma unroll
        for (int i = 0; i < 4; ++i)
            xv[i] = *reinterpret_cast<const float4*>(
                &X[(size_t)(k0t + kq_w * 4 + i) * NPIX + x0 + xq * 4]);
        {
            float xt[4][4] = {
                {xv[0].x, xv[1].x, xv[2].x, xv[3].x},
                {xv[0].y, xv[1].y, xv[2].y, xv[3].y},
                {xv[0].z, xv[1].z, xv[2].z, xv[3].z},
                {xv[0].w, xv[1].w, xv[2].w, xv[3].w}};
#pragma unroll
            for (int j = 0; j < 4; ++j) {
                const int x = xq * 4 + j;
                ushort4 u;
                u.x = f2bf(xt[j][0]); u.y = f2bf(xt[j][1]);
                u.z = f2bf(xt[j][2]); u.w = f2bf(xt[j][3]);
                *reinterpret_cast<ushort4*>(
                    (char*)Bs + x * 128 + ((kq_w ^ (x & 15)) << 3)) = u;
            }
        }
        __syncthreads();

#pragma unroll
        for (int kc = 0; kc < 2; ++kc) {
            const float4 va = (kc == 0) ? av0 : av2;
            const float4 vb = (kc == 0) ? av1 : av3;
            const float a[8] = {va.x, va.y, va.z, va.w, vb.x, vb.y, vb.z, vb.w};
            short8v ah, al;
#pragma unroll
            for (int j = 0; j < 8; ++j) {
                const unsigned short h = f2bf(a[j]);
                ah[j] = (short)h;
                al[j] = (short)f2bf(a[j] - bf2f(h));
            }
#pragma unroll
            for (int nt = 0; nt < 4; ++nt) {
                const int x = nt * 16 + l15;
                const int kq = kc * 8 + l4 * 2;
                ushort4 b0 = *reinterpret_cast<ushort4*>(
                    (char*)Bs + x * 128 + ((kq ^ l15) << 3));
                ushort4 b1 = *reinterpret_cast<ushort4*>(
                    (char*)Bs + x * 128 + (((kq + 1) ^ l15) << 3));
                short8v bh;
                bh[0] = (short)b0.x; bh[1] = (short)b0.y;
                bh[2] = (short)b0.z; bh[3] = (short)b0.w;
                bh[4] = (short)b1.x; bh[5] = (short)b1.y;
                bh[6] = (short)b1.z; bh[7] = (short)b1.w;
                acc[nt] = __builtin_amdgcn_mfma_f32_16x16x32_bf16(ah, bh, acc[nt], 0, 0, 0);
                acc[nt] = __builtin_amdgcn_mfma_f32_16x16x32_bf16(al, bh, acc[nt], 0, 0, 0);
            }
        }
        __syncthreads();
    }

    // Direct dense bf16 store: lane covers (x, 4 consecutive o) -> 8B chunks
#pragma unroll
    for (int nt = 0; nt < 4; ++nt) {
        const int x = nt * 16 + l15;
        ushort4 u;
        u.x = f2bf(acc[nt][0]); u.y = f2bf(acc[nt][1]);
        u.z = f2bf(acc[nt][2]); u.w = f2bf(acc[nt][3]);
        *reinterpret_cast<ushort4*>(
            &out[(size_t)(x0 + x) * OCC + o0 + wv * 16 + l4 * 4]) = u;
    }
}

// ---------------------------------------------------------------------------
// Attention: 512-thread (8-wave) blocks; block = 2x16 pixel tile for one
// (b, head). tid = pixl*16 + l*8 + e : 32 pixels x 2 maps x 8 d-eighths.
// Each thread handles ONE map's dot+acc (halved per-wave work, doubled wave
// count -> 4.5 waves/SIMD). 6x20 bf16 key patch (30 KB) staged by pure 16B
// copies (slabs already bf16) with pre-swizzled source unit (u ^ pos&7).
// No-max exp2 softmax; cross-map (l) combine deferred to one post-loop
// shfl_xor(8) batch. Direct [chan][pix] output (16-pix 64B spans).
// ---------------------------------------------------------------------------
__global__ __launch_bounds__(512, 4) void attn_kernel(
    const unsigned short* __restrict__ ws, float* __restrict__ out)
{
    __shared__ __align__(16) unsigned short kp[2 * NPOS * 64];   // 30720 B

    const int tid = threadIdx.x;
    const int bid = blockIdx.x;
    const int tile = bid % NTILES;
    const int head = (bid / NTILES) % NHEADS;
    const int b = bid / (NTILES * NHEADS);
    const int h0 = (tile / 3) * TH;
    const int w0 = (tile % 3) * TW;

    const unsigned short* qp = ws + (size_t)(0 * NB + b) * SLAB;
    const unsigned short* k1 = ws + (size_t)(1 * NB + b) * SLAB;
    const unsigned short* k2 = ws + (size_t)(2 * NB + b) * SLAB;
    const int co = head * DHEAD;

    // ---- stage key patch: 16B copies, source pre-swizzled by pos&7 ----
#pragma unroll
    for (int it = 0; it < 4; ++it) {
        const int g = it * 512 + tid;
        if (g < 2 * NPOS * 8) {
            const int row = g >> 3;            // 0..239
            const int u = g & 7;               // LDS 16B unit
            const int lm = row >= NPOS;
            const int pos = row - (lm ? NPOS : 0);
            const int pr = pos / PWC, pc = pos - pr * PWC;
            const int hh = h0 + pr - 2, wp = w0 + pc - 2;
            short8v v = {0, 0, 0, 0, 0, 0, 0, 0};
            if (hh >= 0 && hh < HH && wp >= 0 && wp < WWD) {
                const unsigned short* kmap = lm ? k2 : k1;
                v = *reinterpret_cast<const short8v*>(
                    &kmap[(size_t)(hh * WWD + wp) * OCC + co
                          + ((u ^ (pos & 7)) << 3)]);
            }
            *reinterpret_cast<short8v*>(&kp[row * 64 + u * 8]) = v;
        }
    }
    __syncthreads();

    const int e = tid & 7;            // d-eighth (8 chans)
    const int l = (tid >> 3) & 1;     // map
    const int pixl = tid >> 4;        // 0..31
    const int pi = pixl >> 4, pj = pixl & 15;
    const int pix = (h0 + pi) * WWD + (w0 + pj);

    // q fragment (bf16), pre-scaled by 0.125*log2e
    float qd[8];
    {
        short8v qv = *reinterpret_cast<const short8v*>(
            &qp[(size_t)pix * OCC + co + e * 8]);
#pragma unroll
        for (int k = 0; k < 8; ++k)
            qd[k] = bf2f((unsigned short)qv[k]) * SCALE_E;
    }

    const unsigned short* kbase = kp + l * NPOS * 64;

    float den = 0.f;
    float acc[8];
#pragma unroll
    for (int k = 0; k < 8; ++k) acc[k] = 0.f;

#pragma unroll
    for (int r = 0; r < 25; ++r) {
        const int di = r / 5, dj = r % 5;
        const int pos = (pi + di) * PWC + (pj + dj);
        const int p7 = pos & 7;
        short8v kv = *reinterpret_cast<const short8v*>(
            &kbase[pos * 64 + ((e ^ p7) << 3)]);

        float kvf[8];
#pragma unroll
        for (int k = 0; k < 8; ++k) kvf[k] = bf2f((unsigned short)kv[k]);

        float s = 0.f;
#pragma unroll
        for (int k = 0; k < 8; ++k) s += qd[k] * kvf[k];
        s = xreduce8(s);

        const float p = exp2f(s);
        den += p;
#pragma unroll
        for (int k = 0; k < 8; ++k) acc[k] += p * kvf[k];
    }

    // ---- cross-map combine (lane bit 3) ----
    den += __shfl_xor(den, 8, 64);
#pragma unroll
    for (int k = 0; k < 8; ++k) acc[k] += __shfl_xor(acc[k], 8, 64);
    const float rden = 1.f / den;

    // ---- direct output: per chan a 16-pixel 64B span; l splits the chans ----
#pragma unroll
    for (int k = 0; k < 4; ++k) {
        const int ch = co + e * 8 + l * 4 + k;
        out[((size_t)b * OCC + ch) * NPIX + pix] = acc[l * 4 + k] * rden;
    }
}

extern "C" void kernel_launch(void* const* d_in, const int* in_sizes, int n_in,
                              void* d_out, int out_size, void* d_ws, size_t ws_size,
                              hipStream_t stream) {
    const float* kvmap1 = (const float*)d_in[0];
    const float* qmap   = (const float*)d_in[1];
    const float* kvmap2 = (const float*)d_in[2];
    const float* Wq     = (const float*)d_in[3];
    const float* Wkv    = (const float*)d_in[4];
    float* out = (float*)d_out;
    unsigned short* ws = (unsigned short*)d_ws;

    dim3 ggrid(NPIX / 64, OCC / 64, 3 * NB);   // (36, 4, 6)
    proj_mfma<<<ggrid, 256, 0, stream>>>(Wq, Wkv, qmap, kvmap1, kvmap2, ws);

    const int nblocks = NTILES * NHEADS * NB;   // 576
    attn_kernel<<<nblocks, 512, 0, stream>>>(ws, out);
}

// Round 11
// 98.474 us; speedup vs baseline: 1.0431x; 1.0431x over previous
//
#include <hip/hip_runtime.h>

#define HH 48
#define WWD 48
#define CC 256
#define OCC 256
#define NPIX 2304
#define NB 2
#define NHEADS 4
#define DHEAD 64
#define SCALE_E 0.1803368802f   // 0.125 * log2(e); softmax via exp2

// attention tiling: 2x16 pixel tile, 6x20 patch
#define TH 2
#define TW 16
#define PHR 6
#define PWC 20
#define NPOS 120            // PHR*PWC
#define NTILES 72           // (48/2)*(48/16)

#define SLAB ((size_t)NPIX * OCC)   // elements (bf16 ushort)

typedef __attribute__((ext_vector_type(8))) short short8v;
typedef __attribute__((ext_vector_type(4))) float floatx4;

__device__ __forceinline__ unsigned short f2bf(float f) {
    union { float f; unsigned u; } v; v.f = f;
    unsigned r = v.u + 0x7FFFu + ((v.u >> 16) & 1u);   // RNE
    return (unsigned short)(r >> 16);
}
__device__ __forceinline__ float bf2f(unsigned short b) {
    union { unsigned u; float f; } v; v.u = ((unsigned)b) << 16; return v.f;
}

// 8-lane (bits 0..2) all-reduce sum: xor1/xor2 via DPP quad_perm (VALU pipe),
// xor4 via one shfl.
__device__ __forceinline__ float xreduce8(float s) {
    s += __int_as_float(__builtin_amdgcn_update_dpp(
        0, __float_as_int(s), 0xB1, 0xf, 0xf, true));   // [1,0,3,2]
    s += __int_as_float(__builtin_amdgcn_update_dpp(
        0, __float_as_int(s), 0x4E, 0xf, 0xf, true));   // [2,3,0,1]
    s += __shfl_xor(s, 4, 64);
    return s;
}

// ---------------------------------------------------------------------------
// MFMA projection (validated R7/R8): out[x][o] = sum_c W[o][c]*X[c][x].
// A = W hi/lo bf16 split loaded directly from global; B = X^T staged to LDS
// as bf16-hi via in-register 4x4 transpose with 8B XOR swizzle. Output slabs
// stored BF16 (attn consumes bf16 anyway; q gains one rounding ~1e-3).
// ---------------------------------------------------------------------------
__global__ __launch_bounds__(256) void proj_mfma(
    const float* __restrict__ Wq, const float* __restrict__ Wkv,
    const float* __restrict__ qmap, const float* __restrict__ kv1,
    const float* __restrict__ kv2, unsigned short* __restrict__ ws)
{
    __shared__ unsigned short Bs[64 * 64];   // 8 KB, [x][k] bf16 swizzled

    const int z = blockIdx.z;
    const int map = z % 3;
    const int b = z / 3;
    const float* Wmat = (map == 0) ? Wq : Wkv;
    const float* X = ((map == 0) ? qmap : (map == 1) ? kv1 : kv2)
                     + (size_t)b * CC * NPIX;
    unsigned short* out = ws + ((size_t)map * NB + b) * SLAB;

    const int tid = threadIdx.x;
    const int x0 = blockIdx.x * 64;
    const int o0 = blockIdx.y * 64;
    const int lane = tid & 63;
    const int wv = tid >> 6;
    const int l15 = lane & 15;
    const int l4 = lane >> 4;
    const int kq_w = tid >> 4;
    const int xq = tid & 15;

    const float* Arow = Wmat + (size_t)(o0 + wv * 16 + l15) * CC;

    floatx4 acc[4];
#pragma unroll
    for (int nt = 0; nt < 4; ++nt) acc[nt] = (floatx4){0.f, 0.f, 0.f, 0.f};

#pragma unroll
    for (int kt = 0; kt < 4; ++kt) {
        const int k0t = kt * 64;

        float4 av0 = *reinterpret_cast<const float4*>(Arow + k0t + l4 * 8);
        float4 av1 = *reinterpret_cast<const float4*>(Arow + k0t + l4 * 8 + 4);
        float4 av2 = *reinterpret_cast<const float4*>(Arow + k0t + 32 + l4 * 8);
        float4 av3 = *reinterpret_cast<const float4*>(Arow + k0t + 32 + l4 * 8 + 4);

        float4 xv[4];
#pragma unroll
        for (int i = 0; i < 4; ++i)
            xv[i] = *reinterpret_cast<const float4*>(
                &X[(size_t)(k0t + kq_w * 4 + i) * NPIX + x0 + xq * 4]);
        {
            float xt[4][4] = {
                {xv[0].x, xv[1].x, xv[2].x, xv[3].x},
                {xv[0].y, xv[1].y, xv[2].y, xv[3].y},
                {xv[0].z, xv[1].z, xv[2].z, xv[3].z},
                {xv[0].w, xv[1].w, xv[2].w, xv[3].w}};
#pragma unroll
            for (int j = 0; j < 4; ++j) {
                const int x = xq * 4 + j;
                ushort4 u;
                u.x = f2bf(xt[j][0]); u.y = f2bf(xt[j][1]);
                u.z = f2bf(xt[j][2]); u.w = f2bf(xt[j][3]);
                *reinterpret_cast<ushort4*>(
                    (char*)Bs + x * 128 + ((kq_w ^ (x & 15)) << 3)) = u;
            }
        }
        __syncthreads();

#pragma unroll
        for (int kc = 0; kc < 2; ++kc) {
            const float4 va = (kc == 0) ? av0 : av2;
            const float4 vb = (kc == 0) ? av1 : av3;
            const float a[8] = {va.x, va.y, va.z, va.w, vb.x, vb.y, vb.z, vb.w};
            short8v ah, al;
#pragma unroll
            for (int j = 0; j < 8; ++j) {
                const unsigned short h = f2bf(a[j]);
                ah[j] = (short)h;
                al[j] = (short)f2bf(a[j] - bf2f(h));
            }
#pragma unroll
            for (int nt = 0; nt < 4; ++nt) {
                const int x = nt * 16 + l15;
                const int kq = kc * 8 + l4 * 2;
                ushort4 b0 = *reinterpret_cast<ushort4*>(
                    (char*)Bs + x * 128 + ((kq ^ l15) << 3));
                ushort4 b1 = *reinterpret_cast<ushort4*>(
                    (char*)Bs + x * 128 + (((kq + 1) ^ l15) << 3));
                short8v bh;
                bh[0] = (short)b0.x; bh[1] = (short)b0.y;
                bh[2] = (short)b0.z; bh[3] = (short)b0.w;
                bh[4] = (short)b1.x; bh[5] = (short)b1.y;
                bh[6] = (short)b1.z; bh[7] = (short)b1.w;
                acc[nt] = __builtin_amdgcn_mfma_f32_16x16x32_bf16(ah, bh, acc[nt], 0, 0, 0);
                acc[nt] = __builtin_amdgcn_mfma_f32_16x16x32_bf16(al, bh, acc[nt], 0, 0, 0);
            }
        }
        __syncthreads();
    }

#pragma unroll
    for (int nt = 0; nt < 4; ++nt) {
        const int x = nt * 16 + l15;
        ushort4 u;
        u.x = f2bf(acc[nt][0]); u.y = f2bf(acc[nt][1]);
        u.z = f2bf(acc[nt][2]); u.w = f2bf(acc[nt][3]);
        *reinterpret_cast<ushort4*>(
            &out[(size_t)(x0 + x) * OCC + o0 + wv * 16 + l4 * 4]) = u;
    }
}

// ---------------------------------------------------------------------------
// Attention: 512-thread (8-wave) blocks; block = 2x16 pixel tile for one
// (b, head). tid = pixl*16 + l*8 + e : 32 pixels x 2 maps x 8 d-eighths.
// Each thread handles ONE map. 6x20 bf16 key patch (30 KB) staged by 16B
// copies with pre-swizzled source unit. No-max exp2 softmax.
// Cross-map combine (FIXED from R9): thread keeps channels l*4+k, so it
// must RECEIVE partner's acc[l*4+k]; sender therefore transmits
// acc[(1^l)*4+k]. R9 sent acc[l*4+k] -> cross-channel mixing (absmax 0.245).
// Epilogue via padded [chan][pix] LDS tile (stride 33), then re-mapped
// full-line float4 stores (4 consecutive lanes = one 64B line, no RMW).
// ---------------------------------------------------------------------------
__global__ __launch_bounds__(512, 4) void attn_kernel(
    const unsigned short* __restrict__ ws, float* __restrict__ out)
{
    __shared__ __align__(16) unsigned short kp[2 * NPOS * 64];   // 30720 B

    const int tid = threadIdx.x;
    const int bid = blockIdx.x;
    const int tile = bid % NTILES;
    const int head = (bid / NTILES) % NHEADS;
    const int b = bid / (NTILES * NHEADS);
    const int h0 = (tile / 3) * TH;
    const int w0 = (tile % 3) * TW;

    const unsigned short* qp = ws + (size_t)(0 * NB + b) * SLAB;
    const unsigned short* k1 = ws + (size_t)(1 * NB + b) * SLAB;
    const unsigned short* k2 = ws + (size_t)(2 * NB + b) * SLAB;
    const int co = head * DHEAD;

    // ---- stage key patch: 16B copies, source pre-swizzled by pos&7 ----
#pragma unroll
    for (int it = 0; it < 4; ++it) {
        const int g = it * 512 + tid;
        if (g < 2 * NPOS * 8) {
            const int row = g >> 3;            // 0..239
            const int u = g & 7;               // LDS 16B unit
            const int lm = row >= NPOS;
            const int pos = row - (lm ? NPOS : 0);
            const int pr = pos / PWC, pc = pos - pr * PWC;
            const int hh = h0 + pr - 2, wp = w0 + pc - 2;
            short8v v = {0, 0, 0, 0, 0, 0, 0, 0};
            if (hh >= 0 && hh < HH && wp >= 0 && wp < WWD) {
                const unsigned short* kmap = lm ? k2 : k1;
                v = *reinterpret_cast<const short8v*>(
                    &kmap[(size_t)(hh * WWD + wp) * OCC + co
                          + ((u ^ (pos & 7)) << 3)]);
            }
            *reinterpret_cast<short8v*>(&kp[row * 64 + u * 8]) = v;
        }
    }
    __syncthreads();

    const int e = tid & 7;            // d-eighth (8 chans)
    const int l = (tid >> 3) & 1;     // map
    const int pixl = tid >> 4;        // 0..31
    const int pi = pixl >> 4, pj = pixl & 15;
    const int pix = (h0 + pi) * WWD + (w0 + pj);

    // q fragment (bf16), pre-scaled by 0.125*log2e
    float qd[8];
    {
        short8v qv = *reinterpret_cast<const short8v*>(
            &qp[(size_t)pix * OCC + co + e * 8]);
#pragma unroll
        for (int k = 0; k < 8; ++k)
            qd[k] = bf2f((unsigned short)qv[k]) * SCALE_E;
    }

    const unsigned short* kbase = kp + l * NPOS * 64;

    float den = 0.f;
    float acc[8];
#pragma unroll
    for (int k = 0; k < 8; ++k) acc[k] = 0.f;

#pragma unroll
    for (int r = 0; r < 25; ++r) {
        const int di = r / 5, dj = r % 5;
        const int pos = (pi + di) * PWC + (pj + dj);
        const int p7 = pos & 7;
        short8v kv = *reinterpret_cast<const short8v*>(
            &kbase[pos * 64 + ((e ^ p7) << 3)]);

        float kvf[8];
#pragma unroll
        for (int k = 0; k < 8; ++k) kvf[k] = bf2f((unsigned short)kv[k]);

        float s = 0.f;
#pragma unroll
        for (int k = 0; k < 8; ++k) s += qd[k] * kvf[k];
        s = xreduce8(s);

        const float p = exp2f(s);
        den += p;
#pragma unroll
        for (int k = 0; k < 8; ++k) acc[k] += p * kvf[k];
    }

    // ---- cross-map combine (lane bit 3), corrected half-swap ----
    den += __shfl_xor(den, 8, 64);
    const float rden = 1.f / den;
    float r4[4];
#pragma unroll
    for (int k = 0; k < 4; ++k) {
        const float keep = acc[l * 4 + k];        // my map's part of my chans
        const float send = acc[(1 ^ l) * 4 + k];  // my map's part of PARTNER's chans
        r4[k] = (keep + __shfl_xor(send, 8, 64)) * rden;
    }

    // ---- epilogue via LDS: [chan][pix] stride-33 tile, then full-line stores
    __syncthreads();                          // done reading kp
    float* ldo = (float*)kp;                  // 64*33*4 = 8448 B <= 30720
#pragma unroll
    for (int k = 0; k < 4; ++k) {
        ldo[(e * 8 + l * 4 + k) * 33 + pixl] = r4[k];
    }
    __syncthreads();

    {
        const int u = tid & 3;                // 16B chunk within line
        const int idx = tid >> 2;             // 0..127 line id
        const int ch = idx >> 1;              // 0..63
        const int pr = idx & 1;               // tile row
        const float* src = &ldo[ch * 33 + pr * 16 + u * 4];
        float4 v = make_float4(src[0], src[1], src[2], src[3]);
        *reinterpret_cast<float4*>(
            &out[((size_t)b * OCC + co + ch) * NPIX
                 + (h0 + pr) * WWD + w0 + u * 4]) = v;
    }
}

extern "C" void kernel_launch(void* const* d_in, const int* in_sizes, int n_in,
                              void* d_out, int out_size, void* d_ws, size_t ws_size,
                              hipStream_t stream) {
    const float* kvmap1 = (const float*)d_in[0];
    const float* qmap   = (const float*)d_in[1];
    const float* kvmap2 = (const float*)d_in[2];
    const float* Wq     = (const float*)d_in[3];
    const float* Wkv    = (const float*)d_in[4];
    float* out = (float*)d_out;
    unsigned short* ws = (unsigned short*)d_ws;

    dim3 ggrid(NPIX / 64, OCC / 64, 3 * NB);   // (36, 4, 6)
    proj_mfma<<<ggrid, 256, 0, stream>>>(Wq, Wkv, qmap, kvmap1, kvmap2, ws);

    const int nblocks = NTILES * NHEADS * NB;   // 576
    attn_kernel<<<nblocks, 512, 0, stream>>>(ws, out);
}

// Round 12
// 40.793 us; speedup vs baseline: 2.5180x; 2.4140x over previous
//
#include <hip/hip_runtime.h>

#define HH 48
#define WWD 48
#define CC 256
#define OCC 256
#define NPIX 2304
#define NB 2
#define NHEADS 4
#define DHEAD 64
#define SCALE_E 0.1803368802f   // 0.125 * log2(e); softmax via exp2

// attention tiling: 2x16 pixel tile, 6x20 patch
#define TH 2
#define TW 16
#define PHR 6
#define PWC 20
#define NPOS 120            // PHR*PWC
#define NTILES 72           // (48/2)*(48/16)

#define SLAB ((size_t)NPIX * OCC)   // elements (bf16 ushort)

typedef __attribute__((ext_vector_type(8))) short short8v;
typedef __attribute__((ext_vector_type(4))) float floatx4;

__device__ __forceinline__ unsigned short f2bf(float f) {
    union { float f; unsigned u; } v; v.f = f;
    unsigned r = v.u + 0x7FFFu + ((v.u >> 16) & 1u);   // RNE
    return (unsigned short)(r >> 16);
}
__device__ __forceinline__ float bf2f(unsigned short b) {
    union { unsigned u; float f; } v; v.u = ((unsigned)b) << 16; return v.f;
}

// 8-lane (bits 0..2) all-reduce sum: xor1/xor2 via DPP quad_perm (VALU pipe),
// xor4 via one shfl.
__device__ __forceinline__ float xreduce8(float s) {
    s += __int_as_float(__builtin_amdgcn_update_dpp(
        0, __float_as_int(s), 0xB1, 0xf, 0xf, true));   // [1,0,3,2]
    s += __int_as_float(__builtin_amdgcn_update_dpp(
        0, __float_as_int(s), 0x4E, 0xf, 0xf, true));   // [2,3,0,1]
    s += __shfl_xor(s, 4, 64);
    return s;
}

// ---------------------------------------------------------------------------
// MFMA projection (validated R7/R8): out[x][o] = sum_c W[o][c]*X[c][x].
// A = W hi/lo bf16 split loaded directly from global; B = X^T staged to LDS
// as bf16-hi via in-register 4x4 transpose with 8B XOR swizzle. Output slabs
// stored BF16 (attn consumes bf16 anyway; q gains one rounding ~1e-3).
// ---------------------------------------------------------------------------
__global__ __launch_bounds__(256) void proj_mfma(
    const float* __restrict__ Wq, const float* __restrict__ Wkv,
    const float* __restrict__ qmap, const float* __restrict__ kv1,
    const float* __restrict__ kv2, unsigned short* __restrict__ ws)
{
    __shared__ unsigned short Bs[64 * 64];   // 8 KB, [x][k] bf16 swizzled

    const int z = blockIdx.z;
    const int map = z % 3;
    const int b = z / 3;
    const float* Wmat = (map == 0) ? Wq : Wkv;
    const float* X = ((map == 0) ? qmap : (map == 1) ? kv1 : kv2)
                     + (size_t)b * CC * NPIX;
    unsigned short* out = ws + ((size_t)map * NB + b) * SLAB;

    const int tid = threadIdx.x;
    const int x0 = blockIdx.x * 64;
    const int o0 = blockIdx.y * 64;
    const int lane = tid & 63;
    const int wv = tid >> 6;
    const int l15 = lane & 15;
    const int l4 = lane >> 4;
    const int kq_w = tid >> 4;
    const int xq = tid & 15;

    const float* Arow = Wmat + (size_t)(o0 + wv * 16 + l15) * CC;

    floatx4 acc[4];
#pragma unroll
    for (int nt = 0; nt < 4; ++nt) acc[nt] = (floatx4){0.f, 0.f, 0.f, 0.f};

#pragma unroll
    for (int kt = 0; kt < 4; ++kt) {
        const int k0t = kt * 64;

        float4 av0 = *reinterpret_cast<const float4*>(Arow + k0t + l4 * 8);
        float4 av1 = *reinterpret_cast<const float4*>(Arow + k0t + l4 * 8 + 4);
        float4 av2 = *reinterpret_cast<const float4*>(Arow + k0t + 32 + l4 * 8);
        float4 av3 = *reinterpret_cast<const float4*>(Arow + k0t + 32 + l4 * 8 + 4);

        float4 xv[4];
#pragma unroll
        for (int i = 0; i < 4; ++i)
            xv[i] = *reinterpret_cast<const float4*>(
                &X[(size_t)(k0t + kq_w * 4 + i) * NPIX + x0 + xq * 4]);
        {
            float xt[4][4] = {
                {xv[0].x, xv[1].x, xv[2].x, xv[3].x},
                {xv[0].y, xv[1].y, xv[2].y, xv[3].y},
                {xv[0].z, xv[1].z, xv[2].z, xv[3].z},
                {xv[0].w, xv[1].w, xv[2].w, xv[3].w}};
#pragma unroll
            for (int j = 0; j < 4; ++j) {
                const int x = xq * 4 + j;
                ushort4 u;
                u.x = f2bf(xt[j][0]); u.y = f2bf(xt[j][1]);
                u.z = f2bf(xt[j][2]); u.w = f2bf(xt[j][3]);
                *reinterpret_cast<ushort4*>(
                    (char*)Bs + x * 128 + ((kq_w ^ (x & 15)) << 3)) = u;
            }
        }
        __syncthreads();

#pragma unroll
        for (int kc = 0; kc < 2; ++kc) {
            const float4 va = (kc == 0) ? av0 : av2;
            const float4 vb = (kc == 0) ? av1 : av3;
            const float a[8] = {va.x, va.y, va.z, va.w, vb.x, vb.y, vb.z, vb.w};
            short8v ah, al;
#pragma unroll
            for (int j = 0; j < 8; ++j) {
                const unsigned short h = f2bf(a[j]);
                ah[j] = (short)h;
                al[j] = (short)f2bf(a[j] - bf2f(h));
            }
#pragma unroll
            for (int nt = 0; nt < 4; ++nt) {
                const int x = nt * 16 + l15;
                const int kq = kc * 8 + l4 * 2;
                ushort4 b0 = *reinterpret_cast<ushort4*>(
                    (char*)Bs + x * 128 + ((kq ^ l15) << 3));
                ushort4 b1 = *reinterpret_cast<ushort4*>(
                    (char*)Bs + x * 128 + (((kq + 1) ^ l15) << 3));
                short8v bh;
                bh[0] = (short)b0.x; bh[1] = (short)b0.y;
                bh[2] = (short)b0.z; bh[3] = (short)b0.w;
                bh[4] = (short)b1.x; bh[5] = (short)b1.y;
                bh[6] = (short)b1.z; bh[7] = (short)b1.w;
                acc[nt] = __builtin_amdgcn_mfma_f32_16x16x32_bf16(ah, bh, acc[nt], 0, 0, 0);
                acc[nt] = __builtin_amdgcn_mfma_f32_16x16x32_bf16(al, bh, acc[nt], 0, 0, 0);
            }
        }
        __syncthreads();
    }

#pragma unroll
    for (int nt = 0; nt < 4; ++nt) {
        const int x = nt * 16 + l15;
        ushort4 u;
        u.x = f2bf(acc[nt][0]); u.y = f2bf(acc[nt][1]);
        u.z = f2bf(acc[nt][2]); u.w = f2bf(acc[nt][3]);
        *reinterpret_cast<ushort4*>(
            &out[(size_t)(x0 + x) * OCC + o0 + wv * 16 + l4 * 4]) = u;
    }
}

// ---------------------------------------------------------------------------
// Attention: 512-thread (8-wave) blocks; block = 2x16 pixel tile for one
// (b, head). tid = pixl*16 + l*8 + e : 32 pixels x 2 maps x 8 d-eighths.
// Each thread handles ONE map. 6x20 bf16 key patch (30 KB) staged by 16B
// copies with pre-swizzled source unit. No-max exp2 softmax; cross-map
// combine with corrected half-swap (R10). Epilogue via padded [chan][pix]
// LDS tile -> full-line float4 stores.
// R11 FIX: __launch_bounds__(512, 2) instead of (512, 4). The (512,4) bound
// capped VGPR at 64, forcing the ~60-reg live set (qd[8]+acc[8]+kvf[8]+
// addresses + unroll temps) into SCRATCH: 183 MB of deterministic spill
// writes + ~80 MB spill reads per dispatch = the entire R8/R10 regression
// (store-pattern change in R10 moved nothing -> writes were never stores).
// ---------------------------------------------------------------------------
__global__ __launch_bounds__(512, 2) void attn_kernel(
    const unsigned short* __restrict__ ws, float* __restrict__ out)
{
    __shared__ __align__(16) unsigned short kp[2 * NPOS * 64];   // 30720 B

    const int tid = threadIdx.x;
    const int bid = blockIdx.x;
    const int tile = bid % NTILES;
    const int head = (bid / NTILES) % NHEADS;
    const int b = bid / (NTILES * NHEADS);
    const int h0 = (tile / 3) * TH;
    const int w0 = (tile % 3) * TW;

    const unsigned short* qp = ws + (size_t)(0 * NB + b) * SLAB;
    const unsigned short* k1 = ws + (size_t)(1 * NB + b) * SLAB;
    const unsigned short* k2 = ws + (size_t)(2 * NB + b) * SLAB;
    const int co = head * DHEAD;

    // ---- stage key patch: 16B copies, source pre-swizzled by pos&7 ----
#pragma unroll
    for (int it = 0; it < 4; ++it) {
        const int g = it * 512 + tid;
        if (g < 2 * NPOS * 8) {
            const int row = g >> 3;            // 0..239
            const int u = g & 7;               // LDS 16B unit
            const int lm = row >= NPOS;
            const int pos = row - (lm ? NPOS : 0);
            const int pr = pos / PWC, pc = pos - pr * PWC;
            const int hh = h0 + pr - 2, wp = w0 + pc - 2;
            short8v v = {0, 0, 0, 0, 0, 0, 0, 0};
            if (hh >= 0 && hh < HH && wp >= 0 && wp < WWD) {
                const unsigned short* kmap = lm ? k2 : k1;
                v = *reinterpret_cast<const short8v*>(
                    &kmap[(size_t)(hh * WWD + wp) * OCC + co
                          + ((u ^ (pos & 7)) << 3)]);
            }
            *reinterpret_cast<short8v*>(&kp[row * 64 + u * 8]) = v;
        }
    }
    __syncthreads();

    const int e = tid & 7;            // d-eighth (8 chans)
    const int l = (tid >> 3) & 1;     // map
    const int pixl = tid >> 4;        // 0..31
    const int pi = pixl >> 4, pj = pixl & 15;
    const int pix = (h0 + pi) * WWD + (w0 + pj);

    // q fragment (bf16), pre-scaled by 0.125*log2e
    float qd[8];
    {
        short8v qv = *reinterpret_cast<const short8v*>(
            &qp[(size_t)pix * OCC + co + e * 8]);
#pragma unroll
        for (int k = 0; k < 8; ++k)
            qd[k] = bf2f((unsigned short)qv[k]) * SCALE_E;
    }

    const unsigned short* kbase = kp + l * NPOS * 64;

    float den = 0.f;
    float acc[8];
#pragma unroll
    for (int k = 0; k < 8; ++k) acc[k] = 0.f;

#pragma unroll
    for (int r = 0; r < 25; ++r) {
        const int di = r / 5, dj = r % 5;
        const int pos = (pi + di) * PWC + (pj + dj);
        const int p7 = pos & 7;
        short8v kv = *reinterpret_cast<const short8v*>(
            &kbase[pos * 64 + ((e ^ p7) << 3)]);

        float kvf[8];
#pragma unroll
        for (int k = 0; k < 8; ++k) kvf[k] = bf2f((unsigned short)kv[k]);

        float s = 0.f;
#pragma unroll
        for (int k = 0; k < 8; ++k) s += qd[k] * kvf[k];
        s = xreduce8(s);

        const float p = exp2f(s);
        den += p;
#pragma unroll
        for (int k = 0; k < 8; ++k) acc[k] += p * kvf[k];
    }

    // ---- cross-map combine (lane bit 3), corrected half-swap ----
    den += __shfl_xor(den, 8, 64);
    const float rden = 1.f / den;
    float r4[4];
#pragma unroll
    for (int k = 0; k < 4; ++k) {
        const float keep = acc[l * 4 + k];        // my map's part of my chans
        const float send = acc[(1 ^ l) * 4 + k];  // my map's part of PARTNER's chans
        r4[k] = (keep + __shfl_xor(send, 8, 64)) * rden;
    }

    // ---- epilogue via LDS: [chan][pix] stride-33 tile, then full-line stores
    __syncthreads();                          // done reading kp
    float* ldo = (float*)kp;                  // 64*33*4 = 8448 B <= 30720
#pragma unroll
    for (int k = 0; k < 4; ++k) {
        ldo[(e * 8 + l * 4 + k) * 33 + pixl] = r4[k];
    }
    __syncthreads();

    {
        const int u = tid & 3;                // 16B chunk within line
        const int idx = tid >> 2;             // 0..127 line id
        const int ch = idx >> 1;              // 0..63
        const int pr = idx & 1;               // tile row
        const float* src = &ldo[ch * 33 + pr * 16 + u * 4];
        float4 v = make_float4(src[0], src[1], src[2], src[3]);
        *reinterpret_cast<float4*>(
            &out[((size_t)b * OCC + co + ch) * NPIX
                 + (h0 + pr) * WWD + w0 + u * 4]) = v;
    }
}

extern "C" void kernel_launch(void* const* d_in, const int* in_sizes, int n_in,
                              void* d_out, int out_size, void* d_ws, size_t ws_size,
                              hipStream_t stream) {
    const float* kvmap1 = (const float*)d_in[0];
    const float* qmap   = (const float*)d_in[1];
    const float* kvmap2 = (const float*)d_in[2];
    const float* Wq     = (const float*)d_in[3];
    const float* Wkv    = (const float*)d_in[4];
    float* out = (float*)d_out;
    unsigned short* ws = (unsigned short*)d_ws;

    dim3 ggrid(NPIX / 64, OCC / 64, 3 * NB);   // (36, 4, 6)
    proj_mfma<<<ggrid, 256, 0, stream>>>(Wq, Wkv, qmap, kvmap1, kvmap2, ws);

    const int nblocks = NTILES * NHEADS * NB;   // 576
    attn_kernel<<<nblocks, 512, 0, stream>>>(ws, out);
}

// Round 13
// 33.792 us; speedup vs baseline: 3.0397x; 1.2072x over previous
//
#include <hip/hip_runtime.h>

#define HH 48
#define WWD 48
#define CC 256
#define OCC 256
#define NPIX 2304
#define NB 2
#define NHEADS 4
#define DHEAD 64
#define SCALE_E 0.1803368802f   // 0.125 * log2(e); softmax via exp2

// attention tiling: 2x16 pixel tile, 6x20 patch
#define TH 2
#define TW 16
#define PHR 6
#define PWC 20
#define NPOS 120            // PHR*PWC
#define NTILES 72           // (48/2)*(48/16)

#define SLAB ((size_t)NPIX * OCC)   // elements (bf16 ushort)

typedef __attribute__((ext_vector_type(8))) short short8v;
typedef __attribute__((ext_vector_type(4))) float floatx4;

__device__ __forceinline__ unsigned short f2bf(float f) {
    union { float f; unsigned u; } v; v.f = f;
    unsigned r = v.u + 0x7FFFu + ((v.u >> 16) & 1u);   // RNE
    return (unsigned short)(r >> 16);
}
__device__ __forceinline__ float bf2f(unsigned short b) {
    union { unsigned u; float f; } v; v.u = ((unsigned)b) << 16; return v.f;
}

// 8-lane (bits 0..2) all-reduce sum: xor1/xor2 via DPP quad_perm (VALU pipe),
// xor4 via one shfl.
__device__ __forceinline__ float xreduce8(float s) {
    s += __int_as_float(__builtin_amdgcn_update_dpp(
        0, __float_as_int(s), 0xB1, 0xf, 0xf, true));   // [1,0,3,2]
    s += __int_as_float(__builtin_amdgcn_update_dpp(
        0, __float_as_int(s), 0x4E, 0xf, 0xf, true));   // [2,3,0,1]
    s += __shfl_xor(s, 4, 64);
    return s;
}

// ---------------------------------------------------------------------------
// MFMA projection (validated R7/R8/R11, unchanged): out[x][o] =
// sum_c W[o][c]*X[c][x]. A = W hi/lo bf16 split loaded directly from global;
// B = X^T staged to LDS as bf16-hi via in-register 4x4 transpose with 8B XOR
// swizzle. Output slabs stored BF16.
// ---------------------------------------------------------------------------
__global__ __launch_bounds__(256) void proj_mfma(
    const float* __restrict__ Wq, const float* __restrict__ Wkv,
    const float* __restrict__ qmap, const float* __restrict__ kv1,
    const float* __restrict__ kv2, unsigned short* __restrict__ ws)
{
    __shared__ unsigned short Bs[64 * 64];   // 8 KB, [x][k] bf16 swizzled

    const int z = blockIdx.z;
    const int map = z % 3;
    const int b = z / 3;
    const float* Wmat = (map == 0) ? Wq : Wkv;
    const float* X = ((map == 0) ? qmap : (map == 1) ? kv1 : kv2)
                     + (size_t)b * CC * NPIX;
    unsigned short* out = ws + ((size_t)map * NB + b) * SLAB;

    const int tid = threadIdx.x;
    const int x0 = blockIdx.x * 64;
    const int o0 = blockIdx.y * 64;
    const int lane = tid & 63;
    const int wv = tid >> 6;
    const int l15 = lane & 15;
    const int l4 = lane >> 4;
    const int kq_w = tid >> 4;
    const int xq = tid & 15;

    const float* Arow = Wmat + (size_t)(o0 + wv * 16 + l15) * CC;

    floatx4 acc[4];
#pragma unroll
    for (int nt = 0; nt < 4; ++nt) acc[nt] = (floatx4){0.f, 0.f, 0.f, 0.f};

#pragma unroll
    for (int kt = 0; kt < 4; ++kt) {
        const int k0t = kt * 64;

        float4 av0 = *reinterpret_cast<const float4*>(Arow + k0t + l4 * 8);
        float4 av1 = *reinterpret_cast<const float4*>(Arow + k0t + l4 * 8 + 4);
        float4 av2 = *reinterpret_cast<const float4*>(Arow + k0t + 32 + l4 * 8);
        float4 av3 = *reinterpret_cast<const float4*>(Arow + k0t + 32 + l4 * 8 + 4);

        float4 xv[4];
#pragma unroll
        for (int i = 0; i < 4; ++i)
            xv[i] = *reinterpret_cast<const float4*>(
                &X[(size_t)(k0t + kq_w * 4 + i) * NPIX + x0 + xq * 4]);
        {
            float xt[4][4] = {
                {xv[0].x, xv[1].x, xv[2].x, xv[3].x},
                {xv[0].y, xv[1].y, xv[2].y, xv[3].y},
                {xv[0].z, xv[1].z, xv[2].z, xv[3].z},
                {xv[0].w, xv[1].w, xv[2].w, xv[3].w}};
#pragma unroll
            for (int j = 0; j < 4; ++j) {
                const int x = xq * 4 + j;
                ushort4 u;
                u.x = f2bf(xt[j][0]); u.y = f2bf(xt[j][1]);
                u.z = f2bf(xt[j][2]); u.w = f2bf(xt[j][3]);
                *reinterpret_cast<ushort4*>(
                    (char*)Bs + x * 128 + ((kq_w ^ (x & 15)) << 3)) = u;
            }
        }
        __syncthreads();

#pragma unroll
        for (int kc = 0; kc < 2; ++kc) {
            const float4 va = (kc == 0) ? av0 : av2;
            const float4 vb = (kc == 0) ? av1 : av3;
            const float a[8] = {va.x, va.y, va.z, va.w, vb.x, vb.y, vb.z, vb.w};
            short8v ah, al;
#pragma unroll
            for (int j = 0; j < 8; ++j) {
                const unsigned short h = f2bf(a[j]);
                ah[j] = (short)h;
                al[j] = (short)f2bf(a[j] - bf2f(h));
            }
#pragma unroll
            for (int nt = 0; nt < 4; ++nt) {
                const int x = nt * 16 + l15;
                const int kq = kc * 8 + l4 * 2;
                ushort4 b0 = *reinterpret_cast<ushort4*>(
                    (char*)Bs + x * 128 + ((kq ^ l15) << 3));
                ushort4 b1 = *reinterpret_cast<ushort4*>(
                    (char*)Bs + x * 128 + (((kq + 1) ^ l15) << 3));
                short8v bh;
                bh[0] = (short)b0.x; bh[1] = (short)b0.y;
                bh[2] = (short)b0.z; bh[3] = (short)b0.w;
                bh[4] = (short)b1.x; bh[5] = (short)b1.y;
                bh[6] = (short)b1.z; bh[7] = (short)b1.w;
                acc[nt] = __builtin_amdgcn_mfma_f32_16x16x32_bf16(ah, bh, acc[nt], 0, 0, 0);
                acc[nt] = __builtin_amdgcn_mfma_f32_16x16x32_bf16(al, bh, acc[nt], 0, 0, 0);
            }
        }
        __syncthreads();
    }

#pragma unroll
    for (int nt = 0; nt < 4; ++nt) {
        const int x = nt * 16 + l15;
        ushort4 u;
        u.x = f2bf(acc[nt][0]); u.y = f2bf(acc[nt][1]);
        u.z = f2bf(acc[nt][2]); u.w = f2bf(acc[nt][3]);
        *reinterpret_cast<ushort4*>(
            &out[(size_t)(x0 + x) * OCC + o0 + wv * 16 + l4 * 4]) = u;
    }
}

// ---------------------------------------------------------------------------
// Attention (R7 structure + R8 wins): 256-thread (4-wave) blocks; block =
// 2x16 pixel tile for one (b, head). tid = pixl*8 + e : 32 pixels x 8
// d-eighths; each thread handles BOTH maps (no cross-map shuffle).
// bf16 slabs -> staging is pure 16B copies with pre-swizzled source unit.
// No-max exp2 softmax (log2e folded into q scale); 8-lane reduce = 2 DPP
// (VALU pipe) + 1 shfl. Direct scalar stores (intra-block line merge proved
// OK at R7=36.9). __launch_bounds__(256,4) -> VGPR<=128, live set ~80, NO
// spills (R11 lesson: launch_bounds is a register contract).
// ---------------------------------------------------------------------------
__global__ __launch_bounds__(256, 4) void attn_kernel(
    const unsigned short* __restrict__ ws, float* __restrict__ out)
{
    __shared__ __align__(16) unsigned short kp[2 * NPOS * 64];   // 30720 B

    const int tid = threadIdx.x;
    const int bid = blockIdx.x;
    const int tile = bid % NTILES;
    const int head = (bid / NTILES) % NHEADS;
    const int b = bid / (NTILES * NHEADS);
    const int h0 = (tile / 3) * TH;
    const int w0 = (tile % 3) * TW;

    const unsigned short* qp = ws + (size_t)(0 * NB + b) * SLAB;
    const unsigned short* k1 = ws + (size_t)(1 * NB + b) * SLAB;
    const unsigned short* k2 = ws + (size_t)(2 * NB + b) * SLAB;
    const int co = head * DHEAD;

    // ---- stage key patch: 1920 16B copies, source pre-swizzled by pos&7 ----
#pragma unroll
    for (int it = 0; it < 8; ++it) {
        const int g = it * 256 + tid;
        if (g < 2 * NPOS * 8) {
            const int row = g >> 3;            // 0..239
            const int u = g & 7;               // LDS 16B unit
            const int lm = row >= NPOS;
            const int pos = row - (lm ? NPOS : 0);
            const int pr = pos / PWC, pc = pos - pr * PWC;
            const int hh = h0 + pr - 2, wp = w0 + pc - 2;
            short8v v = {0, 0, 0, 0, 0, 0, 0, 0};
            if (hh >= 0 && hh < HH && wp >= 0 && wp < WWD) {
                const unsigned short* kmap = lm ? k2 : k1;
                v = *reinterpret_cast<const short8v*>(
                    &kmap[(size_t)(hh * WWD + wp) * OCC + co
                          + ((u ^ (pos & 7)) << 3)]);
            }
            *reinterpret_cast<short8v*>(&kp[row * 64 + u * 8]) = v;
        }
    }
    __syncthreads();

    const int e = tid & 7;            // d-eighth (8 chans)
    const int pixl = tid >> 3;        // 0..31
    const int pi = pixl >> 4, pj = pixl & 15;
    const int pix = (h0 + pi) * WWD + (w0 + pj);

    // q fragment (bf16), pre-scaled by 0.125*log2e
    float qd[8];
    {
        short8v qv = *reinterpret_cast<const short8v*>(
            &qp[(size_t)pix * OCC + co + e * 8]);
#pragma unroll
        for (int k = 0; k < 8; ++k)
            qd[k] = bf2f((unsigned short)qv[k]) * SCALE_E;
    }

    float den = 0.f;
    float acc[8];
#pragma unroll
    for (int k = 0; k < 8; ++k) acc[k] = 0.f;

#pragma unroll
    for (int r = 0; r < 25; ++r) {
        const int di = r / 5, dj = r % 5;
        const int pos = (pi + di) * PWC + (pj + dj);
        const int uoff = ((e ^ (pos & 7)) << 3);

        short8v ku1 = *reinterpret_cast<const short8v*>(&kp[pos * 64 + uoff]);
        short8v ku2 = *reinterpret_cast<const short8v*>(
            &kp[(NPOS + pos) * 64 + uoff]);

        float k1f[8], k2f[8];
#pragma unroll
        for (int k = 0; k < 8; ++k) {
            k1f[k] = bf2f((unsigned short)ku1[k]);
            k2f[k] = bf2f((unsigned short)ku2[k]);
        }

        float s1 = 0.f, s2 = 0.f;
#pragma unroll
        for (int k = 0; k < 8; ++k) {
            s1 += qd[k] * k1f[k];
            s2 += qd[k] * k2f[k];
        }
        s1 = xreduce8(s1);
        s2 = xreduce8(s2);

        const float p1 = exp2f(s1);
        const float p2 = exp2f(s2);
        den += p1 + p2;
#pragma unroll
        for (int k = 0; k < 8; ++k)
            acc[k] += p1 * k1f[k] + p2 * k2f[k];
    }

    const float rden = 1.f / den;

    // direct output: wave writes 8 chans x 8 consecutive pixels (32B chunks,
    // paired by the sibling wave into full 64B lines within this block)
#pragma unroll
    for (int k = 0; k < 8; ++k) {
        out[((size_t)b * OCC + co + e * 8 + k) * NPIX + pix] = acc[k] * rden;
    }
}

extern "C" void kernel_launch(void* const* d_in, const int* in_sizes, int n_in,
                              void* d_out, int out_size, void* d_ws, size_t ws_size,
                              hipStream_t stream) {
    const float* kvmap1 = (const float*)d_in[0];
    const float* qmap   = (const float*)d_in[1];
    const float* kvmap2 = (const float*)d_in[2];
    const float* Wq     = (const float*)d_in[3];
    const float* Wkv    = (const float*)d_in[4];
    float* out = (float*)d_out;
    unsigned short* ws = (unsigned short*)d_ws;

    dim3 ggrid(NPIX / 64, OCC / 64, 3 * NB);   // (36, 4, 6)
    proj_mfma<<<ggrid, 256, 0, stream>>>(Wq, Wkv, qmap, kvmap1, kvmap2, ws);

    const int nblocks = NTILES * NHEADS * NB;   // 576
    attn_kernel<<<nblocks, 256, 0, stream>>>(ws, out);
}